// Round 1
// baseline (824.368 us; speedup 1.0000x reference)
//
#include <hip/hip_runtime.h>
#include <math.h>

typedef unsigned short u16;
typedef __attribute__((ext_vector_type(8))) short short8;
typedef __attribute__((ext_vector_type(4))) float f32x4;

static __device__ __forceinline__ u16 f2bf(float f) {
    union { float f; unsigned int u; } c; c.f = f;
    unsigned int u = c.u;
    u += 0x7FFF + ((u >> 16) & 1);
    return (u16)(u >> 16);
}

// ---------------- transpose + cast: W[K][N] f32 -> Wt[N][K] bf16 ----------------
__global__ void k_transpose_cast(const float* __restrict__ W, u16* __restrict__ Wt,
                                 int K, int N)
{
    __shared__ float tile[32][33];
    int n0 = blockIdx.x * 32, k0 = blockIdx.y * 32;
    int tx = threadIdx.x, ty = threadIdx.y;
#pragma unroll
    for (int i = 0; i < 4; i++)
        tile[ty + i * 8][tx] = W[(size_t)(k0 + ty + i * 8) * N + n0 + tx];
    __syncthreads();
#pragma unroll
    for (int i = 0; i < 4; i++)
        Wt[(size_t)(n0 + ty + i * 8) * K + k0 + tx] = f2bf(tile[tx][ty + i * 8]);
}

// ---------------- straight cast f32 -> bf16 ----------------
__global__ void k_cast_bf16(const float* __restrict__ in, u16* __restrict__ out, int n)
{
    int i = blockIdx.x * blockDim.x + threadIdx.x;
    if (i < n) out[i] = f2bf(in[i]);
}

// ---------------- LayerNorm over 768, one block per row ----------------
__global__ __launch_bounds__(256) void k_layernorm(
    const float* __restrict__ x, const float* __restrict__ g, const float* __restrict__ b,
    float* __restrict__ outF, u16* __restrict__ outB)
{
    const int row = blockIdx.x, t = threadIdx.x;
    const float* xr = x + (size_t)row * 768;
    float v[3];
#pragma unroll
    for (int i = 0; i < 3; i++) v[i] = xr[t + i * 256];
    __shared__ float sred[4];
    float s = v[0] + v[1] + v[2];
#pragma unroll
    for (int o = 32; o; o >>= 1) s += __shfl_xor(s, o, 64);
    if ((t & 63) == 0) sred[t >> 6] = s;
    __syncthreads();
    float mu = (sred[0] + sred[1] + sred[2] + sred[3]) * (1.0f / 768.0f);
    __syncthreads();
    float q = 0.f;
#pragma unroll
    for (int i = 0; i < 3; i++) { float d = v[i] - mu; q += d * d; }
#pragma unroll
    for (int o = 32; o; o >>= 1) q += __shfl_xor(q, o, 64);
    if ((t & 63) == 0) sred[t >> 6] = q;
    __syncthreads();
    float var = (sred[0] + sred[1] + sred[2] + sred[3]) * (1.0f / 768.0f);
    float rstd = rsqrtf(var + 1e-5f);
#pragma unroll
    for (int i = 0; i < 3; i++) {
        int c = t + i * 256;
        float y = (v[i] - mu) * rstd * g[c] + b[c];
        if (outF) outF[(size_t)row * 768 + c] = y;
        if (outB) outB[(size_t)row * 768 + c] = f2bf(y);
    }
}

// ---------------- GEMM: out[M][N] = A[M][K](bf16) @ Bt[N][K]^T(bf16) + bias ----------------
// optional exact GELU, optional f32 residual, f32 and/or bf16 outputs.
__global__ __launch_bounds__(256) void k_gemm_bt(
    const u16* __restrict__ A, const u16* __restrict__ Bt,
    const float* __restrict__ bias, const float* __restrict__ resid,
    float* __restrict__ outF, u16* __restrict__ outB,
    int M, int N, int K, int do_gelu)
{
    __shared__ u16 As[128 * 32];
    __shared__ u16 Bs[128 * 32];
    const int t = threadIdx.x;
    const int w = t >> 6, l = t & 63;
    const int lr = l & 15, lg = l >> 4;
    const int m0 = blockIdx.y * 128, n0 = blockIdx.x * 128;
    const int wr = (w >> 1) * 64, wc = (w & 1) * 64;

    f32x4 acc[4][4] = {};

    for (int k0 = 0; k0 < K; k0 += 32) {
        __syncthreads();
#pragma unroll
        for (int i = 0; i < 2; i++) {
            int c = i * 256 + t;
            int row = c >> 2, c8 = c & 3;
            *(short8*)&As[c * 8] = *(const short8*)(A + (size_t)(m0 + row) * K + k0 + c8 * 8);
            *(short8*)&Bs[c * 8] = *(const short8*)(Bt + (size_t)(n0 + row) * K + k0 + c8 * 8);
        }
        __syncthreads();
        short8 af[4], bfr[4];
#pragma unroll
        for (int m = 0; m < 4; m++) af[m] = *(const short8*)&As[(wr + m * 16 + lr) * 32 + lg * 8];
#pragma unroll
        for (int n = 0; n < 4; n++) bfr[n] = *(const short8*)&Bs[(wc + n * 16 + lr) * 32 + lg * 8];
#pragma unroll
        for (int m = 0; m < 4; m++)
#pragma unroll
            for (int n = 0; n < 4; n++)
                acc[m][n] = __builtin_amdgcn_mfma_f32_16x16x32_bf16(af[m], bfr[n], acc[m][n], 0, 0, 0);
    }

#pragma unroll
    for (int m = 0; m < 4; m++) {
        int row0 = m0 + wr + m * 16 + lg * 4;
#pragma unroll
        for (int n = 0; n < 4; n++) {
            int col = n0 + wc + n * 16 + lr;
            float bv = bias ? bias[col] : 0.0f;
#pragma unroll
            for (int j = 0; j < 4; j++) {
                float vv = acc[m][n][j] + bv;
                if (do_gelu) vv = 0.5f * vv * (1.0f + erff(vv * 0.70710678118f));
                size_t idx = (size_t)(row0 + j) * N + col;
                if (resid) vv += resid[idx];
                if (outF) outF[idx] = vv;
                if (outB) outB[idx] = f2bf(vv);
            }
        }
    }
}

// ---------------- Flash attention: Q[BT][768] x K/V[BS][768] -> Y[BT][768], hd=64, H=12 ----------------
template<bool CAUSAL>
__global__ __launch_bounds__(256) void k_attn(
    const u16* __restrict__ Q, const u16* __restrict__ K,
    const u16* __restrict__ V, u16* __restrict__ Y,
    int Tq, int Skv)
{
    const int qt = blockIdx.x, bh = blockIdx.y;
    const int b = bh / 12, h = bh % 12;
    const int t = threadIdx.x, w = t >> 6, l = t & 63;
    const int lr = l & 15, lg = l >> 4;
    const int q0 = qt * 64;

    const u16* Qb = Q + (size_t)b * Tq * 768 + h * 64;
    const u16* Kb = K + (size_t)b * Skv * 768 + h * 64;
    const u16* Vb = V + (size_t)b * Skv * 768 + h * 64;

    __shared__ u16 Ks[64 * 72];
    __shared__ u16 Vt[64 * 72];
    __shared__ u16 Ps[4][16 * 72];

    short8 aq[2];
    {
        const u16* qr = Qb + (size_t)(q0 + w * 16 + lr) * 768 + lg * 8;
        aq[0] = *(const short8*)(qr);
        aq[1] = *(const short8*)(qr + 32);
    }

    f32x4 acc[4] = {};
    float m_run[4] = { -INFINITY, -INFINITY, -INFINITY, -INFINITY };
    float l_run[4] = {};

    const int ntiles = CAUSAL ? (qt + 1) : (Skv / 64);
    for (int kt = 0; kt < ntiles; kt++) {
        const int kv0 = kt * 64;
        __syncthreads();   // previous iter's PV done before overwriting K/V tiles
#pragma unroll
        for (int i = 0; i < 2; i++) {
            int c = i * 256 + t;
            int row = c >> 3, c8 = c & 7;
            short8 kvv = *(const short8*)(Kb + (size_t)(kv0 + row) * 768 + c8 * 8);
            *(short8*)&Ks[row * 72 + c8 * 8] = kvv;
            short8 vvv = *(const short8*)(Vb + (size_t)(kv0 + row) * 768 + c8 * 8);
#pragma unroll
            for (int j = 0; j < 8; j++) Vt[(c8 * 8 + j) * 72 + row] = (u16)vvv[j];
        }
        __syncthreads();

        // S = Q K^T
        f32x4 s[4];
#pragma unroll
        for (int c = 0; c < 4; c++) {
            const u16* kb = &Ks[(c * 16 + lr) * 72 + lg * 8];
            f32x4 a = {};
            a = __builtin_amdgcn_mfma_f32_16x16x32_bf16(aq[0], *(const short8*)kb, a, 0, 0, 0);
            a = __builtin_amdgcn_mfma_f32_16x16x32_bf16(aq[1], *(const short8*)(kb + 32), a, 0, 0, 0);
            s[c] = a;
        }

        // scale + causal mask + row max (rows live across 16 lanes: shfl-xor 1..8)
        float mx[4];
#pragma unroll
        for (int j = 0; j < 4; j++) {
#pragma unroll
            for (int c = 0; c < 4; c++) {
                float sv = s[c][j] * 0.125f;
                if (CAUSAL && kt == ntiles - 1) {
                    int qrow = q0 + w * 16 + lg * 4 + j;
                    int kcol = kv0 + c * 16 + lr;
                    if (kcol > qrow) sv = -1e30f;
                }
                s[c][j] = sv;
            }
            float mv = fmaxf(fmaxf(s[0][j], s[1][j]), fmaxf(s[2][j], s[3][j]));
#pragma unroll
            for (int o = 1; o < 16; o <<= 1) mv = fmaxf(mv, __shfl_xor(mv, o, 64));
            mx[j] = mv;
        }

        float rs[4];
#pragma unroll
        for (int j = 0; j < 4; j++) {
            float mnew = fmaxf(m_run[j], mx[j]);
            float sc = __expf(m_run[j] - mnew);   // exp(-inf - finite) = 0
            m_run[j] = mnew;
            l_run[j] *= sc;
#pragma unroll
            for (int c = 0; c < 4; c++) acc[c][j] *= sc;
            float r = 0.f;
#pragma unroll
            for (int c = 0; c < 4; c++) {
                float p = __expf(s[c][j] - mnew);
                s[c][j] = p;
                r += p;
            }
            rs[j] = r;
        }
#pragma unroll
        for (int j = 0; j < 4; j++) {
            float r = rs[j];
#pragma unroll
            for (int o = 1; o < 16; o <<= 1) r += __shfl_xor(r, o, 64);
            l_run[j] += r;
        }

        // P -> LDS (per-wave area), then PV
        u16* pw = Ps[w];
#pragma unroll
        for (int j = 0; j < 4; j++)
#pragma unroll
            for (int c = 0; c < 4; c++)
                pw[(lg * 4 + j) * 72 + c * 16 + lr] = f2bf(s[c][j]);
        __syncthreads();

        const u16* pr = Ps[w] + lr * 72 + lg * 8;
        short8 pa0 = *(const short8*)(pr);
        short8 pa1 = *(const short8*)(pr + 32);
#pragma unroll
        for (int c = 0; c < 4; c++) {
            const u16* vb = &Vt[(c * 16 + lr) * 72 + lg * 8];
            acc[c] = __builtin_amdgcn_mfma_f32_16x16x32_bf16(pa0, *(const short8*)vb, acc[c], 0, 0, 0);
            acc[c] = __builtin_amdgcn_mfma_f32_16x16x32_bf16(pa1, *(const short8*)(vb + 32), acc[c], 0, 0, 0);
        }
    }

#pragma unroll
    for (int j = 0; j < 4; j++) {
        float inv = 1.0f / l_run[j];
        size_t yb = (size_t)(b * Tq + q0 + w * 16 + lg * 4 + j) * 768 + h * 64;
#pragma unroll
        for (int c = 0; c < 4; c++)
            Y[yb + c * 16 + lr] = f2bf(acc[c][j] * inv);
    }
}

// ---------------- launcher ----------------
extern "C" void kernel_launch(void* const* d_in, const int* in_sizes, int n_in,
                              void* d_out, int out_size, void* d_ws, size_t ws_size,
                              hipStream_t stream)
{
    (void)in_sizes; (void)n_in; (void)out_size; (void)ws_size;
    const float* x    = (const float*)d_in[0];
    const float* enc  = (const float*)d_in[1];
    const float* ln1g = (const float*)d_in[2];
    const float* ln1b = (const float*)d_in[3];
    const float* ln2g = (const float*)d_in[4];
    const float* ln2b = (const float*)d_in[5];
    const float* sWq  = (const float*)d_in[6];
    const float* sbq  = (const float*)d_in[7];
    const float* sWk  = (const float*)d_in[8];
    const float* sbk  = (const float*)d_in[9];
    const float* sWv  = (const float*)d_in[10];
    const float* sbv  = (const float*)d_in[11];
    const float* sWo  = (const float*)d_in[12];
    const float* sbo  = (const float*)d_in[13];
    const float* cWq  = (const float*)d_in[14];
    const float* cbq  = (const float*)d_in[15];
    const float* cWk  = (const float*)d_in[16];
    const float* cbk  = (const float*)d_in[17];
    const float* cWv  = (const float*)d_in[18];
    const float* cbv  = (const float*)d_in[19];
    const float* cWo  = (const float*)d_in[20];
    const float* cbo  = (const float*)d_in[21];
    const float* mW1  = (const float*)d_in[22];
    const float* mb1  = (const float*)d_in[23];
    const float* mW2  = (const float*)d_in[24];
    const float* mb2  = (const float*)d_in[25];
    float* out = (float*)d_out;

    const int Bb = 4, T = 2048, S = 512, C = 768, P = 1024, F = 3072;
    const int M = Bb * T;    // 8192
    const int MS = Bb * S;   // 2048

    char* ws = (char*)d_ws;
    size_t off = 0;
    auto alloc = [&](size_t bytes) -> void* {
        void* p = ws + off;
        off += (bytes + 255) & ~(size_t)255;
        return p;
    };

    u16* sWqT = (u16*)alloc((size_t)C * C * 2);
    u16* sWkT = (u16*)alloc((size_t)C * C * 2);
    u16* sWvT = (u16*)alloc((size_t)C * C * 2);
    u16* sWoT = (u16*)alloc((size_t)C * C * 2);
    u16* cWqT = (u16*)alloc((size_t)C * C * 2);
    u16* cWkT = (u16*)alloc((size_t)C * P * 2);
    u16* cWvT = (u16*)alloc((size_t)C * P * 2);
    u16* cWoT = (u16*)alloc((size_t)C * C * 2);
    u16* mW1T = (u16*)alloc((size_t)F * C * 2);
    u16* mW2T = (u16*)alloc((size_t)C * F * 2);
    u16* encbf = (u16*)alloc((size_t)MS * P * 2);
    float* slotA = (float*)alloc((size_t)M * C * 4);  // xn, later x2
    float* slotB = (float*)alloc((size_t)M * C * 4);  // x1
    u16*   slotC = (u16*)alloc((size_t)M * C * 2);    // xn_bf -> x1_bf -> h2_bf
    u16*   big   = (u16*)alloc((size_t)M * F * 2);    // q|k|v|y  then  mid

    u16* qbf = big;
    u16* kbf = big + (size_t)M * C;
    u16* vbf = big + (size_t)2 * M * C;
    u16* ybf = big + (size_t)3 * M * C;
    u16* q2bf = qbf;    // reuse after self-attn consumed
    u16* k2bf = kbf;
    u16* v2bf = vbf;
    u16* y2bf = ybf;
    u16* midbf = big;

    float* xn = slotA;
    float* x2 = slotA;
    float* x1 = slotB;
    u16* xbf = slotC;

    dim3 tb(32, 8);
    k_transpose_cast<<<dim3(C / 32, C / 32), tb, 0, stream>>>(sWq, sWqT, C, C);
    k_transpose_cast<<<dim3(C / 32, C / 32), tb, 0, stream>>>(sWk, sWkT, C, C);
    k_transpose_cast<<<dim3(C / 32, C / 32), tb, 0, stream>>>(sWv, sWvT, C, C);
    k_transpose_cast<<<dim3(C / 32, C / 32), tb, 0, stream>>>(sWo, sWoT, C, C);
    k_transpose_cast<<<dim3(C / 32, C / 32), tb, 0, stream>>>(cWq, cWqT, C, C);
    k_transpose_cast<<<dim3(C / 32, P / 32), tb, 0, stream>>>(cWk, cWkT, P, C);
    k_transpose_cast<<<dim3(C / 32, P / 32), tb, 0, stream>>>(cWv, cWvT, P, C);
    k_transpose_cast<<<dim3(C / 32, C / 32), tb, 0, stream>>>(cWo, cWoT, C, C);
    k_transpose_cast<<<dim3(F / 32, C / 32), tb, 0, stream>>>(mW1, mW1T, C, F);
    k_transpose_cast<<<dim3(C / 32, F / 32), tb, 0, stream>>>(mW2, mW2T, F, C);

    k_cast_bf16<<<(MS * P + 255) / 256, 256, 0, stream>>>(enc, encbf, MS * P);

    k_layernorm<<<M, 256, 0, stream>>>(x, ln1g, ln1b, xn, xbf);

    dim3 g768(C / 128, M / 128);
    k_gemm_bt<<<g768, 256, 0, stream>>>(xbf, sWqT, sbq, nullptr, nullptr, qbf, M, C, C, 0);
    k_gemm_bt<<<g768, 256, 0, stream>>>(xbf, sWkT, sbk, nullptr, nullptr, kbf, M, C, C, 0);
    k_gemm_bt<<<g768, 256, 0, stream>>>(xbf, sWvT, sbv, nullptr, nullptr, vbf, M, C, C, 0);

    k_attn<true><<<dim3(T / 64, Bb * 12), 256, 0, stream>>>(qbf, kbf, vbf, ybf, T, T);

    k_gemm_bt<<<g768, 256, 0, stream>>>(ybf, sWoT, sbo, xn, x1, xbf, M, C, C, 0);

    k_gemm_bt<<<g768, 256, 0, stream>>>(xbf, cWqT, cbq, nullptr, nullptr, q2bf, M, C, C, 0);
    dim3 gkv(C / 128, MS / 128);
    k_gemm_bt<<<gkv, 256, 0, stream>>>(encbf, cWkT, cbk, nullptr, nullptr, k2bf, MS, C, P, 0);
    k_gemm_bt<<<gkv, 256, 0, stream>>>(encbf, cWvT, cbv, nullptr, nullptr, v2bf, MS, C, P, 0);

    k_attn<false><<<dim3(T / 64, Bb * 12), 256, 0, stream>>>(q2bf, k2bf, v2bf, y2bf, T, S);

    k_gemm_bt<<<g768, 256, 0, stream>>>(y2bf, cWoT, cbo, x1, x2, nullptr, M, C, C, 0);

    k_layernorm<<<M, 256, 0, stream>>>(x2, ln2g, ln2b, nullptr, xbf);

    dim3 gm1(F / 128, M / 128);
    k_gemm_bt<<<gm1, 256, 0, stream>>>(xbf, mW1T, mb1, nullptr, nullptr, midbf, M, F, C, 1);

    k_gemm_bt<<<g768, 256, 0, stream>>>(midbf, mW2T, mb2, x2, out, nullptr, M, C, F, 0);
}

// Round 3
// 665.295 us; speedup vs baseline: 1.2391x; 1.2391x over previous
//
#include <hip/hip_runtime.h>
#include <math.h>

typedef unsigned short u16;
typedef __attribute__((ext_vector_type(8))) short short8;
typedef __attribute__((ext_vector_type(4))) short bf16x4;
typedef __attribute__((ext_vector_type(4))) float f32x4;

static __device__ __forceinline__ u16 f2bf(float f) {
    union { float f; unsigned int u; } c; c.f = f;
    unsigned int u = c.u;
    u += 0x7FFF + ((u >> 16) & 1);
    return (u16)(u >> 16);
}

#define GLOAD16(g, s) __builtin_amdgcn_global_load_lds( \
    (const __attribute__((address_space(1))) void*)(g), \
    (__attribute__((address_space(3))) void*)(s), 16, 0, 0)

// ---------------- transpose + cast: W[K][N] f32 -> Wt[N][K] bf16 ----------------
__global__ void k_transpose_cast(const float* __restrict__ W, u16* __restrict__ Wt,
                                 int K, int N)
{
    __shared__ float tile[32][33];
    int n0 = blockIdx.x * 32, k0 = blockIdx.y * 32;
    int tx = threadIdx.x, ty = threadIdx.y;
#pragma unroll
    for (int i = 0; i < 4; i++)
        tile[ty + i * 8][tx] = W[(size_t)(k0 + ty + i * 8) * N + n0 + tx];
    __syncthreads();
#pragma unroll
    for (int i = 0; i < 4; i++)
        Wt[(size_t)(n0 + ty + i * 8) * K + k0 + tx] = f2bf(tile[tx][ty + i * 8]);
}

// ---------------- straight cast f32 -> bf16 ----------------
__global__ void k_cast_bf16(const float* __restrict__ in, u16* __restrict__ out, int n)
{
    int i = blockIdx.x * blockDim.x + threadIdx.x;
    if (i < n) out[i] = f2bf(in[i]);
}

// ---------------- LayerNorm over 768, one block per row ----------------
__global__ __launch_bounds__(256) void k_layernorm(
    const float* __restrict__ x, const float* __restrict__ g, const float* __restrict__ b,
    float* __restrict__ outF, u16* __restrict__ outB)
{
    const int row = blockIdx.x, t = threadIdx.x;
    const float* xr = x + (size_t)row * 768;
    float v[3];
#pragma unroll
    for (int i = 0; i < 3; i++) v[i] = xr[t + i * 256];
    __shared__ float sred[4];
    float s = v[0] + v[1] + v[2];
#pragma unroll
    for (int o = 32; o; o >>= 1) s += __shfl_xor(s, o, 64);
    if ((t & 63) == 0) sred[t >> 6] = s;
    __syncthreads();
    float mu = (sred[0] + sred[1] + sred[2] + sred[3]) * (1.0f / 768.0f);
    __syncthreads();
    float q = 0.f;
#pragma unroll
    for (int i = 0; i < 3; i++) { float d = v[i] - mu; q += d * d; }
#pragma unroll
    for (int o = 32; o; o >>= 1) q += __shfl_xor(q, o, 64);
    if ((t & 63) == 0) sred[t >> 6] = q;
    __syncthreads();
    float var = (sred[0] + sred[1] + sred[2] + sred[3]) * (1.0f / 768.0f);
    float rstd = rsqrtf(var + 1e-5f);
#pragma unroll
    for (int i = 0; i < 3; i++) {
        int c = t + i * 256;
        float y = (v[i] - mu) * rstd * g[c] + b[c];
        if (outF) outF[(size_t)row * 768 + c] = y;
        if (outB) outB[(size_t)row * 768 + c] = f2bf(y);
    }
}

// ---------------- GEMM: out[M][N] = A[M][K](bf16) @ Bt[N][K]^T(bf16) + bias ----------------
// m97 structure: global_load_lds width-16 staging into linear [128][32] LDS.
// vT_S != 0: write outB transposed as [b][h=12][d=64][S=vT_S] (for attention V).
__global__ __launch_bounds__(256) void k_gemm_bt(
    const u16* __restrict__ A, const u16* __restrict__ Bt,
    const float* __restrict__ bias, const float* __restrict__ resid,
    float* __restrict__ outF, u16* __restrict__ outB,
    int M, int N, int K, int do_gelu, int vT_S)
{
    __shared__ u16 As[128 * 32];
    __shared__ u16 Bs[128 * 32];
    const int t = threadIdx.x;
    const int w = t >> 6, l = t & 63;
    const int lr = l & 15, lg = l >> 4;
    const int m0 = blockIdx.y * 128, n0 = blockIdx.x * 128;
    const int wr = (w >> 1) * 64, wc = (w & 1) * 64;

    // staging: per-lane global addr, wave-uniform LDS base (+lane*16B implicit)
    const int srow = t >> 2;          // 0..63
    const int skk = (t & 3) * 8;      // 0,8,16,24
    const u16* ga0 = A + (size_t)(m0 + srow) * K + skk;
    const u16* ga1 = A + (size_t)(m0 + 64 + srow) * K + skk;
    const u16* gb0 = Bt + (size_t)(n0 + srow) * K + skk;
    const u16* gb1 = Bt + (size_t)(n0 + 64 + srow) * K + skk;
    u16* lA0 = &As[w * 512];
    u16* lA1 = &As[2048 + w * 512];
    u16* lB0 = &Bs[w * 512];
    u16* lB1 = &Bs[2048 + w * 512];

    f32x4 acc[4][4] = {};

    for (int k0 = 0; k0 < K; k0 += 32) {
        __syncthreads();
        GLOAD16(ga0 + k0, lA0);
        GLOAD16(ga1 + k0, lA1);
        GLOAD16(gb0 + k0, lB0);
        GLOAD16(gb1 + k0, lB1);
        __syncthreads();
        short8 af[4], bfr[4];
#pragma unroll
        for (int m = 0; m < 4; m++) af[m] = *(const short8*)&As[(wr + m * 16 + lr) * 32 + lg * 8];
#pragma unroll
        for (int n = 0; n < 4; n++) bfr[n] = *(const short8*)&Bs[(wc + n * 16 + lr) * 32 + lg * 8];
#pragma unroll
        for (int m = 0; m < 4; m++)
#pragma unroll
            for (int n = 0; n < 4; n++)
                acc[m][n] = __builtin_amdgcn_mfma_f32_16x16x32_bf16(af[m], bfr[n], acc[m][n], 0, 0, 0);
    }

#pragma unroll
    for (int m = 0; m < 4; m++) {
        int row0 = m0 + wr + m * 16 + lg * 4;
#pragma unroll
        for (int n = 0; n < 4; n++) {
            int col = n0 + wc + n * 16 + lr;
            float bv = bias ? bias[col] : 0.0f;
            float vv[4];
#pragma unroll
            for (int j = 0; j < 4; j++) {
                float v = acc[m][n][j] + bv;
                if (do_gelu) v = 0.5f * v * (1.0f + erff(v * 0.70710678118f));
                vv[j] = v;
            }
            if (vT_S) {
                int bq = row0 / vT_S, s = row0 % vT_S;
                bf16x4 pk;
#pragma unroll
                for (int j = 0; j < 4; j++) pk[j] = (short)f2bf(vv[j]);
                *(bf16x4*)&outB[((size_t)((bq * 12 + (col >> 6)) * 64 + (col & 63))) * vT_S + s] = pk;
            } else {
#pragma unroll
                for (int j = 0; j < 4; j++) {
                    size_t idx = (size_t)(row0 + j) * N + col;
                    float v = vv[j];
                    if (resid) v += resid[idx];
                    if (outF) outF[idx] = v;
                    if (outB) outB[idx] = f2bf(v);
                }
            }
        }
    }
}

// ---------------- Flash attention, QBLK=128, KV tile 64, swizzled LDS ----------------
// Q,K: [B][T][768] bf16 (head-major cols). Vt: [B*12][64][Skv] bf16 (pre-transposed).
template<bool CAUSAL>
__global__ __launch_bounds__(256) void k_attn(
    const u16* __restrict__ Q, const u16* __restrict__ K,
    const u16* __restrict__ Vt, u16* __restrict__ Y,
    int Tq, int Skv)
{
    const int bh = blockIdx.x;                 // 0..47
    const int b = bh / 12, h = bh % 12;
    const int qt = CAUSAL ? ((int)gridDim.y - 1 - (int)blockIdx.y) : blockIdx.y;
    const int q0 = qt * 128;
    const int t = threadIdx.x, w = t >> 6, l = t & 63;
    const int lr = l & 15, lg = l >> 4;
    const int swz = (lr & 7) << 3;

    const u16* Qb = Q + (size_t)b * Tq * 768 + h * 64;
    const u16* Kb = K + (size_t)b * Skv * 768 + h * 64;
    const u16* Vb = Vt + (size_t)bh * 64 * Skv;

    __shared__ u16 Ks[64 * 64];
    __shared__ u16 Vs[64 * 64];
    __shared__ u16 Ps[4][32 * 64];

    // Q fragments: wave owns rows q0 + w*32 .. +31 (two 16-row subtiles)
    short8 aq[2][2];
#pragma unroll
    for (int qm = 0; qm < 2; qm++) {
        const u16* qr = Qb + (size_t)(q0 + w * 32 + qm * 16 + lr) * 768 + lg * 8;
        aq[qm][0] = *(const short8*)(qr);
        aq[qm][1] = *(const short8*)(qr + 32);
    }

    f32x4 acc[2][4] = {};
    float mrun[2][4], lrun[2][4];
#pragma unroll
    for (int qm = 0; qm < 2; qm++)
#pragma unroll
        for (int j = 0; j < 4; j++) { mrun[qm][j] = -INFINITY; lrun[qm][j] = 0.f; }

    const int ntiles = CAUSAL ? (2 * qt + 2) : (Skv / 64);
    for (int kt = 0; kt < ntiles; kt++) {
        const int kv0 = kt * 64;
        __syncthreads();
        // stage K [s][d] and Vt [d][s], both row-swizzled (elem ^= (row&7)<<3)
#pragma unroll
        for (int sw = 0; sw < 2; sw++) {
            int idx = sw * 256 + t;
            int row = idx >> 3, db = (idx & 7) * 8;
            short8 kv = *(const short8*)(Kb + (size_t)(kv0 + row) * 768 + db);
            *(short8*)&Ks[row * 64 + (db ^ ((row & 7) << 3))] = kv;
            short8 vv = *(const short8*)(Vb + (size_t)row * Skv + kv0 + db);
            *(short8*)&Vs[row * 64 + (db ^ ((row & 7) << 3))] = vv;
        }
        __syncthreads();

        // S = Q K^T
        f32x4 s[2][4];
#pragma unroll
        for (int c = 0; c < 4; c++) {
            const short8 kb0 = *(const short8*)&Ks[(c * 16 + lr) * 64 + ((lg * 8) ^ swz)];
            const short8 kb1 = *(const short8*)&Ks[(c * 16 + lr) * 64 + ((32 | (lg * 8)) ^ swz)];
#pragma unroll
            for (int qm = 0; qm < 2; qm++) {
                f32x4 a = {};
                a = __builtin_amdgcn_mfma_f32_16x16x32_bf16(aq[qm][0], kb0, a, 0, 0, 0);
                a = __builtin_amdgcn_mfma_f32_16x16x32_bf16(aq[qm][1], kb1, a, 0, 0, 0);
                s[qm][c] = a;
            }
        }

        const bool masked = CAUSAL && (kt >= ntiles - 2);
#pragma unroll
        for (int qm = 0; qm < 2; qm++) {
            float mx[4];
#pragma unroll
            for (int j = 0; j < 4; j++) {
#pragma unroll
                for (int c = 0; c < 4; c++) {
                    float sv = s[qm][c][j] * 0.125f;
                    if (masked) {
                        int qrow = q0 + w * 32 + qm * 16 + lg * 4 + j;
                        int kcol = kv0 + c * 16 + lr;
                        if (kcol > qrow) sv = -1e30f;
                    }
                    s[qm][c][j] = sv;
                }
                float mv = fmaxf(fmaxf(s[qm][0][j], s[qm][1][j]), fmaxf(s[qm][2][j], s[qm][3][j]));
#pragma unroll
                for (int o = 1; o < 16; o <<= 1) mv = fmaxf(mv, __shfl_xor(mv, o, 64));
                mx[j] = mv;
            }
            float rs[4];
#pragma unroll
            for (int j = 0; j < 4; j++) {
                float mnew = fmaxf(mrun[qm][j], mx[j]);
                float sc = __expf(mrun[qm][j] - mnew);
                mrun[qm][j] = mnew;
                lrun[qm][j] *= sc;
#pragma unroll
                for (int c = 0; c < 4; c++) acc[qm][c][j] *= sc;
                float r = 0.f;
#pragma unroll
                for (int c = 0; c < 4; c++) {
                    float p = __expf(s[qm][c][j] - mnew);
                    s[qm][c][j] = p;
                    r += p;
                }
                rs[j] = r;
            }
#pragma unroll
            for (int j = 0; j < 4; j++) {
                float r = rs[j];
#pragma unroll
                for (int o = 1; o < 16; o <<= 1) r += __shfl_xor(r, o, 64);
                lrun[qm][j] += r;
            }
            // P -> per-wave swizzled LDS (no block barrier needed)
            u16* pw = Ps[w];
#pragma unroll
            for (int j = 0; j < 4; j++) {
                int prow = qm * 16 + lg * 4 + j;
                int psw = (prow & 7) << 3;
#pragma unroll
                for (int c = 0; c < 4; c++)
                    pw[prow * 64 + ((c * 16 + lr) ^ psw)] = f2bf(s[qm][c][j]);
            }
        }

        // PV
#pragma unroll
        for (int qm = 0; qm < 2; qm++) {
            const short8 pa0 = *(const short8*)&Ps[w][(qm * 16 + lr) * 64 + ((lg * 8) ^ swz)];
            const short8 pa1 = *(const short8*)&Ps[w][(qm * 16 + lr) * 64 + ((32 | (lg * 8)) ^ swz)];
#pragma unroll
            for (int c = 0; c < 4; c++) {
                const short8 vb0 = *(const short8*)&Vs[(c * 16 + lr) * 64 + ((lg * 8) ^ swz)];
                const short8 vb1 = *(const short8*)&Vs[(c * 16 + lr) * 64 + ((32 | (lg * 8)) ^ swz)];
                acc[qm][c] = __builtin_amdgcn_mfma_f32_16x16x32_bf16(pa0, vb0, acc[qm][c], 0, 0, 0);
                acc[qm][c] = __builtin_amdgcn_mfma_f32_16x16x32_bf16(pa1, vb1, acc[qm][c], 0, 0, 0);
            }
        }
    }

#pragma unroll
    for (int qm = 0; qm < 2; qm++)
#pragma unroll
        for (int j = 0; j < 4; j++) {
            float inv = 1.0f / lrun[qm][j];
            size_t yb = (size_t)(b * Tq + q0 + w * 32 + qm * 16 + lg * 4 + j) * 768 + h * 64;
#pragma unroll
            for (int c = 0; c < 4; c++)
                Y[yb + c * 16 + lr] = f2bf(acc[qm][c][j] * inv);
        }
}

// ---------------- launcher ----------------
extern "C" void kernel_launch(void* const* d_in, const int* in_sizes, int n_in,
                              void* d_out, int out_size, void* d_ws, size_t ws_size,
                              hipStream_t stream)
{
    (void)in_sizes; (void)n_in; (void)out_size; (void)ws_size;
    const float* x    = (const float*)d_in[0];
    const float* enc  = (const float*)d_in[1];
    const float* ln1g = (const float*)d_in[2];
    const float* ln1b = (const float*)d_in[3];
    const float* ln2g = (const float*)d_in[4];
    const float* ln2b = (const float*)d_in[5];
    const float* sWq  = (const float*)d_in[6];
    const float* sbq  = (const float*)d_in[7];
    const float* sWk  = (const float*)d_in[8];
    const float* sbk  = (const float*)d_in[9];
    const float* sWv  = (const float*)d_in[10];
    const float* sbv  = (const float*)d_in[11];
    const float* sWo  = (const float*)d_in[12];
    const float* sbo  = (const float*)d_in[13];
    const float* cWq  = (const float*)d_in[14];
    const float* cbq  = (const float*)d_in[15];
    const float* cWk  = (const float*)d_in[16];
    const float* cbk  = (const float*)d_in[17];
    const float* cWv  = (const float*)d_in[18];
    const float* cbv  = (const float*)d_in[19];
    const float* cWo  = (const float*)d_in[20];
    const float* cbo  = (const float*)d_in[21];
    const float* mW1  = (const float*)d_in[22];
    const float* mb1  = (const float*)d_in[23];
    const float* mW2  = (const float*)d_in[24];
    const float* mb2  = (const float*)d_in[25];
    float* out = (float*)d_out;

    const int Bb = 4, T = 2048, S = 512, C = 768, P = 1024, F = 3072;
    const int M = Bb * T;    // 8192
    const int MS = Bb * S;   // 2048

    char* ws = (char*)d_ws;
    size_t off = 0;
    auto alloc = [&](size_t bytes) -> void* {
        void* p = ws + off;
        off += (bytes + 255) & ~(size_t)255;
        return p;
    };

    u16* sWqT = (u16*)alloc((size_t)C * C * 2);
    u16* sWkT = (u16*)alloc((size_t)C * C * 2);
    u16* sWvT = (u16*)alloc((size_t)C * C * 2);
    u16* sWoT = (u16*)alloc((size_t)C * C * 2);
    u16* cWqT = (u16*)alloc((size_t)C * C * 2);
    u16* cWkT = (u16*)alloc((size_t)C * P * 2);
    u16* cWvT = (u16*)alloc((size_t)C * P * 2);
    u16* cWoT = (u16*)alloc((size_t)C * C * 2);
    u16* mW1T = (u16*)alloc((size_t)F * C * 2);
    u16* mW2T = (u16*)alloc((size_t)C * F * 2);
    u16* encbf = (u16*)alloc((size_t)MS * P * 2);
    float* slotA = (float*)alloc((size_t)M * C * 4);  // xn, later x2
    float* slotB = (float*)alloc((size_t)M * C * 4);  // x1
    u16*   slotC = (u16*)alloc((size_t)M * C * 2);    // xn_bf -> x1_bf -> h2_bf
    u16*   big   = (u16*)alloc((size_t)M * F * 2);    // q|k|v|y  then  mid

    u16* qbf = big;
    u16* kbf = big + (size_t)M * C;
    u16* vbf = big + (size_t)2 * M * C;   // vT layout [B*12][64][2048]
    u16* ybf = big + (size_t)3 * M * C;
    u16* q2bf = qbf;
    u16* k2bf = kbf;
    u16* v2bf = vbf;                       // vT layout [B*12][64][512]
    u16* y2bf = ybf;
    u16* midbf = big;

    float* xn = slotA;
    float* x2 = slotA;
    float* x1 = slotB;
    u16* xbf = slotC;

    dim3 tb(32, 8);
    k_transpose_cast<<<dim3(C / 32, C / 32), tb, 0, stream>>>(sWq, sWqT, C, C);
    k_transpose_cast<<<dim3(C / 32, C / 32), tb, 0, stream>>>(sWk, sWkT, C, C);
    k_transpose_cast<<<dim3(C / 32, C / 32), tb, 0, stream>>>(sWv, sWvT, C, C);
    k_transpose_cast<<<dim3(C / 32, C / 32), tb, 0, stream>>>(sWo, sWoT, C, C);
    k_transpose_cast<<<dim3(C / 32, C / 32), tb, 0, stream>>>(cWq, cWqT, C, C);
    k_transpose_cast<<<dim3(C / 32, P / 32), tb, 0, stream>>>(cWk, cWkT, P, C);
    k_transpose_cast<<<dim3(C / 32, P / 32), tb, 0, stream>>>(cWv, cWvT, P, C);
    k_transpose_cast<<<dim3(C / 32, C / 32), tb, 0, stream>>>(cWo, cWoT, C, C);
    k_transpose_cast<<<dim3(F / 32, C / 32), tb, 0, stream>>>(mW1, mW1T, C, F);
    k_transpose_cast<<<dim3(C / 32, F / 32), tb, 0, stream>>>(mW2, mW2T, F, C);

    k_cast_bf16<<<(MS * P + 255) / 256, 256, 0, stream>>>(enc, encbf, MS * P);

    k_layernorm<<<M, 256, 0, stream>>>(x, ln1g, ln1b, xn, xbf);

    dim3 g768(C / 128, M / 128);
    k_gemm_bt<<<g768, 256, 0, stream>>>(xbf, sWqT, sbq, nullptr, nullptr, qbf, M, C, C, 0, 0);
    k_gemm_bt<<<g768, 256, 0, stream>>>(xbf, sWkT, sbk, nullptr, nullptr, kbf, M, C, C, 0, 0);
    k_gemm_bt<<<g768, 256, 0, stream>>>(xbf, sWvT, sbv, nullptr, nullptr, vbf, M, C, C, 0, T);

    k_attn<true><<<dim3(Bb * 12, T / 128), 256, 0, stream>>>(qbf, kbf, vbf, ybf, T, T);

    k_gemm_bt<<<g768, 256, 0, stream>>>(ybf, sWoT, sbo, xn, x1, xbf, M, C, C, 0, 0);

    k_gemm_bt<<<g768, 256, 0, stream>>>(xbf, cWqT, cbq, nullptr, nullptr, q2bf, M, C, C, 0, 0);
    dim3 gkv(C / 128, MS / 128);
    k_gemm_bt<<<gkv, 256, 0, stream>>>(encbf, cWkT, cbk, nullptr, nullptr, k2bf, MS, C, P, 0, 0);
    k_gemm_bt<<<gkv, 256, 0, stream>>>(encbf, cWvT, cbv, nullptr, nullptr, v2bf, MS, C, P, 0, S);

    k_attn<false><<<dim3(Bb * 12, T / 128), 256, 0, stream>>>(q2bf, k2bf, v2bf, y2bf, T, S);

    k_gemm_bt<<<g768, 256, 0, stream>>>(y2bf, cWoT, cbo, x1, x2, nullptr, M, C, C, 0, 0);

    k_layernorm<<<M, 256, 0, stream>>>(x2, ln2g, ln2b, nullptr, xbf);

    dim3 gm1(F / 128, M / 128);
    k_gemm_bt<<<gm1, 256, 0, stream>>>(xbf, mW1T, mb1, nullptr, nullptr, midbf, M, F, C, 1, 0);

    k_gemm_bt<<<g768, 256, 0, stream>>>(midbf, mW2T, mb2, x2, out, nullptr, M, C, F, 0, 0);
}

// Round 4
// 542.236 us; speedup vs baseline: 1.5203x; 1.2269x over previous
//
#include <hip/hip_runtime.h>
#include <math.h>

typedef unsigned short u16;
typedef __attribute__((ext_vector_type(8))) short short8;
typedef __attribute__((ext_vector_type(4))) short bf16x4;
typedef __attribute__((ext_vector_type(4))) float f32x4;

static __device__ __forceinline__ u16 f2bf(float f) {
    union { float f; unsigned int u; } c; c.f = f;
    unsigned int u = c.u;
    u += 0x7FFF + ((u >> 16) & 1);
    return (u16)(u >> 16);
}
static __device__ __forceinline__ float bf2f(u16 u) {
    union { unsigned int i; float f; } c; c.i = ((unsigned int)u) << 16;
    return c.f;
}

#define GLOAD16(g, s) __builtin_amdgcn_global_load_lds( \
    (const __attribute__((address_space(1))) void*)(g), \
    (__attribute__((address_space(3))) void*)(s), 16, 0, 0)

// ---------------- merged prep: 10 weight transposes (f32->bf16 [N][K]) + enc cast ----------------
struct PrepArgs {
    const float* src[11];
    u16* dst[11];
    int K[11];
    int N[11];
    int end[11];   // exclusive prefix of block counts
    int cnt;
};

__global__ void k_prep(PrepArgs a)
{
    __shared__ float tile[32][33];
    const int bid = blockIdx.x;
    int e = 0;
    while (e < a.cnt - 1 && bid >= a.end[e]) e++;
    const int local = bid - (e ? a.end[e - 1] : 0);
    const float* __restrict__ src = a.src[e];
    u16* __restrict__ dst = a.dst[e];
    const int K = a.K[e], N = a.N[e];
    const int tx = threadIdx.x, ty = threadIdx.y;

    if (K == 0) {   // flat cast of N elements
        size_t base = (size_t)local * 2048 + (size_t)(ty * 32 + tx) * 8;
        float4 v0 = *(const float4*)(src + base);
        float4 v1 = *(const float4*)(src + base + 4);
        short8 o;
        o[0] = (short)f2bf(v0.x); o[1] = (short)f2bf(v0.y);
        o[2] = (short)f2bf(v0.z); o[3] = (short)f2bf(v0.w);
        o[4] = (short)f2bf(v1.x); o[5] = (short)f2bf(v1.y);
        o[6] = (short)f2bf(v1.z); o[7] = (short)f2bf(v1.w);
        *(short8*)&dst[base] = o;
        return;
    }
    const int nbx = N / 32;
    const int bx = local % nbx, by = local / nbx;
    const int n0 = bx * 32, k0 = by * 32;
#pragma unroll
    for (int i = 0; i < 4; i++)
        tile[ty + i * 8][tx] = src[(size_t)(k0 + ty + i * 8) * N + n0 + tx];
    __syncthreads();
#pragma unroll
    for (int i = 0; i < 4; i++)
        dst[(size_t)(n0 + ty + i * 8) * K + k0 + tx] = f2bf(tile[tx][ty + i * 8]);
}

// ---------------- LayerNorm over 768, one block per row ----------------
__global__ __launch_bounds__(256) void k_layernorm(
    const float* __restrict__ x, const float* __restrict__ g, const float* __restrict__ b,
    float* __restrict__ outF, u16* __restrict__ outB)
{
    const int row = blockIdx.x, t = threadIdx.x;
    const float* xr = x + (size_t)row * 768;
    float v[3];
#pragma unroll
    for (int i = 0; i < 3; i++) v[i] = xr[t + i * 256];
    __shared__ float sred[4];
    float s = v[0] + v[1] + v[2];
#pragma unroll
    for (int o = 32; o; o >>= 1) s += __shfl_xor(s, o, 64);
    if ((t & 63) == 0) sred[t >> 6] = s;
    __syncthreads();
    float mu = (sred[0] + sred[1] + sred[2] + sred[3]) * (1.0f / 768.0f);
    __syncthreads();
    float q = 0.f;
#pragma unroll
    for (int i = 0; i < 3; i++) { float d = v[i] - mu; q += d * d; }
#pragma unroll
    for (int o = 32; o; o >>= 1) q += __shfl_xor(q, o, 64);
    if ((t & 63) == 0) sred[t >> 6] = q;
    __syncthreads();
    float var = (sred[0] + sred[1] + sred[2] + sred[3]) * (1.0f / 768.0f);
    float rstd = rsqrtf(var + 1e-5f);
#pragma unroll
    for (int i = 0; i < 3; i++) {
        int c = t + i * 256;
        float y = (v[i] - mu) * rstd * g[c] + b[c];
        if (outF) outF[(size_t)row * 768 + c] = y;
        if (outB) outB[(size_t)row * 768 + c] = f2bf(y);
    }
}

// ---------------- GEMM out[M][N] = A[M][K] @ Bt[N][K]^T + bias ----------------
// BN: 128 (4 waves 2x2, acc[4][4]) or 64 (4 waves 4x1, acc[2][4]).
// mode 0: plain (bias b1, optional resid/outF/outB full-N layout, optional gelu)
// mode 2: QKV split: col<768 -> outB[row][col] (+b1); <1536 -> outK (+b2); else outV vT (+b3)
// mode 3: KV split:  col<768 -> outB (+b1); else outV vT (+b3)
// vT store: [bq*12+head][d][s] with s = row % 2^vT_log
template<int BN>
__global__ __launch_bounds__(256) void k_gemm(
    const u16* __restrict__ A, const u16* __restrict__ Bt,
    const float* __restrict__ b1, const float* __restrict__ b2, const float* __restrict__ b3,
    const float* __restrict__ resid,
    float* __restrict__ outF, u16* __restrict__ outB, u16* __restrict__ outK, u16* __restrict__ outV,
    int M, int N, int K, int do_gelu, int mode, int vT_log)
{
    constexpr int MR = (BN == 128) ? 4 : 2;
    __shared__ u16 As[128 * 32];
    __shared__ u16 Bs[BN * 32];
    const int t = threadIdx.x;
    const int w = t >> 6, l = t & 63;
    const int lr = l & 15, lg = l >> 4;
    const int m0 = blockIdx.y * 128, n0 = blockIdx.x * BN;
    const int wr = (BN == 128) ? ((w >> 1) * 64) : (w * 32);
    const int wc = (BN == 128) ? ((w & 1) * 64) : 0;

    const int srow = t >> 2;
    const int skk = (t & 3) * 8;
    const u16* ga0 = A + (size_t)(m0 + srow) * K + skk;
    const u16* ga1 = A + (size_t)(m0 + 64 + srow) * K + skk;
    const u16* gb0 = Bt + (size_t)(n0 + srow) * K + skk;
    const u16* gb1 = (BN == 128) ? (Bt + (size_t)(n0 + 64 + srow) * K + skk) : nullptr;
    u16* lA0 = &As[w * 512];
    u16* lA1 = &As[2048 + w * 512];
    u16* lB0 = &Bs[w * 512];
    u16* lB1 = (BN == 128) ? &Bs[2048 + w * 512] : nullptr;

    f32x4 acc[MR][4] = {};

    for (int k0 = 0; k0 < K; k0 += 32) {
        __syncthreads();
        GLOAD16(ga0 + k0, lA0);
        GLOAD16(ga1 + k0, lA1);
        GLOAD16(gb0 + k0, lB0);
        if (BN == 128) GLOAD16(gb1 + k0, lB1);
        __syncthreads();
        short8 af[MR], bfr[4];
#pragma unroll
        for (int m = 0; m < MR; m++) af[m] = *(const short8*)&As[(wr + m * 16 + lr) * 32 + lg * 8];
#pragma unroll
        for (int n = 0; n < 4; n++) bfr[n] = *(const short8*)&Bs[(wc + n * 16 + lr) * 32 + lg * 8];
#pragma unroll
        for (int m = 0; m < MR; m++)
#pragma unroll
            for (int n = 0; n < 4; n++)
                acc[m][n] = __builtin_amdgcn_mfma_f32_16x16x32_bf16(af[m], bfr[n], acc[m][n], 0, 0, 0);
    }

#pragma unroll
    for (int m = 0; m < MR; m++) {
        int row0 = m0 + wr + m * 16 + lg * 4;
#pragma unroll
        for (int n = 0; n < 4; n++) {
            int col = n0 + wc + n * 16 + lr;
            // segment select (uniform per n iteration: boundaries are multiples of 64)
            const float* bp = b1; int lc = col; u16* tgt = outB; int vT = 0;
            if (mode == 2) {
                if (col >= 1536)     { bp = b3; lc = col - 1536; tgt = outV; vT = 1; }
                else if (col >= 768) { bp = b2; lc = col - 768;  tgt = outK; }
            } else if (mode == 3) {
                if (col >= 768)      { bp = b3; lc = col - 768;  tgt = outV; vT = 1; }
            }
            float bv = bp[lc];
            float vv[4];
#pragma unroll
            for (int j = 0; j < 4; j++) {
                float v = acc[m][n][j] + bv;
                if (do_gelu) v = 0.5f * v * (1.0f + erff(v * 0.70710678118f));
                vv[j] = v;
            }
            if (mode == 0) {
#pragma unroll
                for (int j = 0; j < 4; j++) {
                    size_t idx = (size_t)(row0 + j) * N + col;
                    float v = vv[j];
                    if (resid) v += resid[idx];
                    if (outF) outF[idx] = v;
                    if (outB) outB[idx] = f2bf(v);
                }
            } else if (!vT) {
#pragma unroll
                for (int j = 0; j < 4; j++)
                    tgt[(size_t)(row0 + j) * 768 + lc] = f2bf(vv[j]);
            } else {
                int head = lc >> 6, d = lc & 63;
                int bq = row0 >> vT_log, s = row0 & ((1 << vT_log) - 1);
                bf16x4 pk;
#pragma unroll
                for (int j = 0; j < 4; j++) pk[j] = (short)f2bf(vv[j]);
                *(bf16x4*)&tgt[((size_t)((bq * 12 + head) * 64 + d) << vT_log) + s] = pk;
            }
        }
    }
}

// ---------------- Flash attention, QBLK=128, KV tile 64, swizzled LDS ----------------
// Q,K: [B][*][768] bf16 (head-major cols). Vt: [B*12][64][Skv] bf16 (pre-transposed).
// Q pre-scaled by 0.125*log2e at load; softmax in exp2 domain; defer-max (THR=8).
template<bool CAUSAL>
__global__ __launch_bounds__(256) void k_attn(
    const u16* __restrict__ Q, const u16* __restrict__ K,
    const u16* __restrict__ Vt, u16* __restrict__ Y,
    int Tq, int Skv)
{
    const int bh = blockIdx.x;
    const int b = bh / 12, h = bh % 12;
    const int qt = CAUSAL ? ((int)gridDim.y - 1 - (int)blockIdx.y) : blockIdx.y;
    const int q0 = qt * 128;
    const int t = threadIdx.x, w = t >> 6, l = t & 63;
    const int lr = l & 15, lg = l >> 4;
    const int swz = (lr & 7) << 3;
    const float QSC = 0.125f * 1.44269504088896f;

    const u16* Qb = Q + (size_t)b * Tq * 768 + h * 64;
    const u16* Kb = K + (size_t)b * Skv * 768 + h * 64;
    const u16* Vb = Vt + (size_t)bh * 64 * Skv;

    __shared__ u16 Ks[64 * 64];
    __shared__ u16 Vs[64 * 64];
    __shared__ u16 Ps[4][32 * 64];

    short8 aq[2][2];
#pragma unroll
    for (int qm = 0; qm < 2; qm++) {
        const u16* qr = Qb + (size_t)(q0 + w * 32 + qm * 16 + lr) * 768 + lg * 8;
#pragma unroll
        for (int hh = 0; hh < 2; hh++) {
            short8 raw = *(const short8*)(qr + hh * 32);
            short8 sc;
#pragma unroll
            for (int i = 0; i < 8; i++) sc[i] = (short)f2bf(bf2f((u16)raw[i]) * QSC);
            aq[qm][hh] = sc;
        }
    }

    f32x4 acc[2][4] = {};
    float mrun[2][4], lrun[2][4];
#pragma unroll
    for (int qm = 0; qm < 2; qm++)
#pragma unroll
        for (int j = 0; j < 4; j++) { mrun[qm][j] = -INFINITY; lrun[qm][j] = 0.f; }

    const int ntiles = CAUSAL ? (2 * qt + 2) : (Skv / 64);
    for (int kt = 0; kt < ntiles; kt++) {
        const int kv0 = kt * 64;
        __syncthreads();
#pragma unroll
        for (int sw = 0; sw < 2; sw++) {
            int idx = sw * 256 + t;
            int row = idx >> 3, db = (idx & 7) * 8;
            short8 kv = *(const short8*)(Kb + (size_t)(kv0 + row) * 768 + db);
            *(short8*)&Ks[row * 64 + (db ^ ((row & 7) << 3))] = kv;
            short8 vvv = *(const short8*)(Vb + (size_t)row * Skv + kv0 + db);
            *(short8*)&Vs[row * 64 + (db ^ ((row & 7) << 3))] = vvv;
        }
        __syncthreads();

        // S = Q K^T (log2 domain)
        f32x4 s[2][4];
        __builtin_amdgcn_s_setprio(1);
#pragma unroll
        for (int c = 0; c < 4; c++) {
            const short8 kb0 = *(const short8*)&Ks[(c * 16 + lr) * 64 + ((lg * 8) ^ swz)];
            const short8 kb1 = *(const short8*)&Ks[(c * 16 + lr) * 64 + ((32 | (lg * 8)) ^ swz)];
#pragma unroll
            for (int qm = 0; qm < 2; qm++) {
                f32x4 a = {};
                a = __builtin_amdgcn_mfma_f32_16x16x32_bf16(aq[qm][0], kb0, a, 0, 0, 0);
                a = __builtin_amdgcn_mfma_f32_16x16x32_bf16(aq[qm][1], kb1, a, 0, 0, 0);
                s[qm][c] = a;
            }
        }
        __builtin_amdgcn_s_setprio(0);

        const bool masked = CAUSAL && (kt >= ntiles - 2);
#pragma unroll
        for (int qm = 0; qm < 2; qm++) {
            if (masked) {
#pragma unroll
                for (int j = 0; j < 4; j++) {
                    int qrow = q0 + w * 32 + qm * 16 + lg * 4 + j;
#pragma unroll
                    for (int c = 0; c < 4; c++) {
                        int kcol = kv0 + c * 16 + lr;
                        if (kcol > qrow) s[qm][c][j] = -1e30f;
                    }
                }
            }
            float mx[4];
#pragma unroll
            for (int j = 0; j < 4; j++) {
                float mv = fmaxf(fmaxf(s[qm][0][j], s[qm][1][j]), fmaxf(s[qm][2][j], s[qm][3][j]));
#pragma unroll
                for (int o = 1; o < 16; o <<= 1) mv = fmaxf(mv, __shfl_xor(mv, o, 64));
                mx[j] = mv;
            }
            // defer-max: skip rescale when max growth <= 8 (factor 256 in exp2 domain)
            float need = mx[0] - mrun[qm][0];
#pragma unroll
            for (int j = 1; j < 4; j++) need = fmaxf(need, mx[j] - mrun[qm][j]);
            if (!__all(need <= 8.0f)) {
#pragma unroll
                for (int j = 0; j < 4; j++) {
                    float mnew = fmaxf(mrun[qm][j], mx[j]);
                    float sc = exp2f(mrun[qm][j] - mnew);
                    mrun[qm][j] = mnew;
                    lrun[qm][j] *= sc;
#pragma unroll
                    for (int c = 0; c < 4; c++) acc[qm][c][j] *= sc;
                }
            }
            float rs[4];
#pragma unroll
            for (int j = 0; j < 4; j++) {
                float r = 0.f;
#pragma unroll
                for (int c = 0; c < 4; c++) {
                    float p = exp2f(s[qm][c][j] - mrun[qm][j]);
                    s[qm][c][j] = p;
                    r += p;
                }
                rs[j] = r;
            }
#pragma unroll
            for (int j = 0; j < 4; j++) {
                float r = rs[j];
#pragma unroll
                for (int o = 1; o < 16; o <<= 1) r += __shfl_xor(r, o, 64);
                lrun[qm][j] += r;
            }
            u16* pw = Ps[w];
#pragma unroll
            for (int j = 0; j < 4; j++) {
                int prow = qm * 16 + lg * 4 + j;
                int psw = (prow & 7) << 3;
#pragma unroll
                for (int c = 0; c < 4; c++)
                    pw[prow * 64 + ((c * 16 + lr) ^ psw)] = f2bf(s[qm][c][j]);
            }
        }

        // PV
        __builtin_amdgcn_s_setprio(1);
#pragma unroll
        for (int qm = 0; qm < 2; qm++) {
            const short8 pa0 = *(const short8*)&Ps[w][(qm * 16 + lr) * 64 + ((lg * 8) ^ swz)];
            const short8 pa1 = *(const short8*)&Ps[w][(qm * 16 + lr) * 64 + ((32 | (lg * 8)) ^ swz)];
#pragma unroll
            for (int c = 0; c < 4; c++) {
                const short8 vb0 = *(const short8*)&Vs[(c * 16 + lr) * 64 + ((lg * 8) ^ swz)];
                const short8 vb1 = *(const short8*)&Vs[(c * 16 + lr) * 64 + ((32 | (lg * 8)) ^ swz)];
                acc[qm][c] = __builtin_amdgcn_mfma_f32_16x16x32_bf16(pa0, vb0, acc[qm][c], 0, 0, 0);
                acc[qm][c] = __builtin_amdgcn_mfma_f32_16x16x32_bf16(pa1, vb1, acc[qm][c], 0, 0, 0);
            }
        }
        __builtin_amdgcn_s_setprio(0);
    }

#pragma unroll
    for (int qm = 0; qm < 2; qm++)
#pragma unroll
        for (int j = 0; j < 4; j++) {
            float inv = 1.0f / lrun[qm][j];
            size_t yb = (size_t)(b * Tq + q0 + w * 32 + qm * 16 + lg * 4 + j) * 768 + h * 64;
#pragma unroll
            for (int c = 0; c < 4; c++)
                Y[yb + c * 16 + lr] = f2bf(acc[qm][c][j] * inv);
        }
}

// ---------------- launcher ----------------
extern "C" void kernel_launch(void* const* d_in, const int* in_sizes, int n_in,
                              void* d_out, int out_size, void* d_ws, size_t ws_size,
                              hipStream_t stream)
{
    (void)in_sizes; (void)n_in; (void)out_size; (void)ws_size;
    const float* x    = (const float*)d_in[0];
    const float* enc  = (const float*)d_in[1];
    const float* ln1g = (const float*)d_in[2];
    const float* ln1b = (const float*)d_in[3];
    const float* ln2g = (const float*)d_in[4];
    const float* ln2b = (const float*)d_in[5];
    const float* sWq  = (const float*)d_in[6];
    const float* sbq  = (const float*)d_in[7];
    const float* sWk  = (const float*)d_in[8];
    const float* sbk  = (const float*)d_in[9];
    const float* sWv  = (const float*)d_in[10];
    const float* sbv  = (const float*)d_in[11];
    const float* sWo  = (const float*)d_in[12];
    const float* sbo  = (const float*)d_in[13];
    const float* cWq  = (const float*)d_in[14];
    const float* cbq  = (const float*)d_in[15];
    const float* cWk  = (const float*)d_in[16];
    const float* cbk  = (const float*)d_in[17];
    const float* cWv  = (const float*)d_in[18];
    const float* cbv  = (const float*)d_in[19];
    const float* cWo  = (const float*)d_in[20];
    const float* cbo  = (const float*)d_in[21];
    const float* mW1  = (const float*)d_in[22];
    const float* mb1  = (const float*)d_in[23];
    const float* mW2  = (const float*)d_in[24];
    const float* mb2  = (const float*)d_in[25];
    float* out = (float*)d_out;

    const int Bb = 4, T = 2048, S = 512, C = 768, P = 1024, F = 3072;
    const int M = Bb * T;    // 8192
    const int MS = Bb * S;   // 2048

    char* ws = (char*)d_ws;
    size_t off = 0;
    auto alloc = [&](size_t bytes) -> void* {
        void* p = ws + off;
        off += (bytes + 255) & ~(size_t)255;
        return p;
    };

    u16* wqkvT = (u16*)alloc((size_t)3 * C * C * 2);   // [2304][768]
    u16* sWoT  = (u16*)alloc((size_t)C * C * 2);
    u16* cWqT  = (u16*)alloc((size_t)C * C * 2);
    u16* ckvT  = (u16*)alloc((size_t)2 * C * P * 2);   // [1536][1024]
    u16* cWoT  = (u16*)alloc((size_t)C * C * 2);
    u16* mW1T  = (u16*)alloc((size_t)F * C * 2);
    u16* mW2T  = (u16*)alloc((size_t)C * F * 2);
    u16* encbf = (u16*)alloc((size_t)MS * P * 2);
    float* slotA = (float*)alloc((size_t)M * C * 4);   // xn, later x2
    float* slotB = (float*)alloc((size_t)M * C * 4);   // x1
    u16*   slotC = (u16*)alloc((size_t)M * C * 2);     // xbf (normed/bf16 stream)
    u16*   big   = (u16*)alloc((size_t)M * F * 2);     // q|k|v|y then mid

    u16* qbf = big;
    u16* kbf = big + (size_t)M * C;
    u16* vbf = big + (size_t)2 * M * C;   // vT layout [48][64][2048]
    u16* ybf = big + (size_t)3 * M * C;
    u16* midbf = big;

    float* xn = slotA;
    float* x2 = slotA;
    float* x1 = slotB;
    u16* xbf = slotC;

    // ---- merged prep ----
    PrepArgs pa;
    const float* srcs[11] = { sWq, sWk, sWv, sWo, cWq, cWk, cWv, cWo, mW1, mW2, enc };
    u16* dsts[11] = { wqkvT, wqkvT + (size_t)C * C, wqkvT + (size_t)2 * C * C,
                      sWoT, cWqT, ckvT, ckvT + (size_t)C * P, cWoT, mW1T, mW2T, encbf };
    int Ks_[11] = { C, C, C, C, C, P, P, C, C, F, 0 };
    int Ns_[11] = { C, C, C, C, C, C, C, C, F, C, MS * P };
    int cum = 0;
    for (int i = 0; i < 11; i++) {
        pa.src[i] = srcs[i]; pa.dst[i] = dsts[i]; pa.K[i] = Ks_[i]; pa.N[i] = Ns_[i];
        int nb = Ks_[i] ? (Ns_[i] / 32) * (Ks_[i] / 32) : (Ns_[i] / 2048);
        cum += nb; pa.end[i] = cum;
    }
    pa.cnt = 11;
    k_prep<<<cum, dim3(32, 8), 0, stream>>>(pa);

    k_layernorm<<<M, 256, 0, stream>>>(x, ln1g, ln1b, xn, xbf);

    // QKV fused: N = 2304, BN=128, grid 18x64
    k_gemm<128><<<dim3(18, 64), 256, 0, stream>>>(
        xbf, wqkvT, sbq, sbk, sbv, nullptr, nullptr, qbf, kbf, vbf, M, 2304, C, 0, 2, 11);

    k_attn<true><<<dim3(Bb * 12, T / 128), 256, 0, stream>>>(qbf, kbf, vbf, ybf, T, T);

    // attn out: BN=64, grid 12x64; resid=xn -> x1 (f32) + xbf (bf16)
    k_gemm<64><<<dim3(12, 64), 256, 0, stream>>>(
        ybf, sWoT, sbo, nullptr, nullptr, xn, x1, xbf, nullptr, nullptr, M, C, C, 0, 0, 0);

    // cross Q: BN=64
    k_gemm<64><<<dim3(12, 64), 256, 0, stream>>>(
        xbf, cWqT, cbq, nullptr, nullptr, nullptr, nullptr, qbf, nullptr, nullptr, M, C, C, 0, 0, 0);

    // cross K/V fused: N=1536, K=1024, M=2048, BN=64, grid 24x16
    k_gemm<64><<<dim3(24, 16), 256, 0, stream>>>(
        encbf, ckvT, cbk, nullptr, cbv, nullptr, nullptr, kbf, nullptr, vbf, MS, 1536, P, 0, 3, 9);

    k_attn<false><<<dim3(Bb * 12, T / 128), 256, 0, stream>>>(qbf, kbf, vbf, ybf, T, S);

    // cross out: resid=x1 -> x2 (f32)
    k_gemm<64><<<dim3(12, 64), 256, 0, stream>>>(
        ybf, cWoT, cbo, nullptr, nullptr, x1, x2, nullptr, nullptr, nullptr, M, C, C, 0, 0, 0);

    k_layernorm<<<M, 256, 0, stream>>>(x2, ln2g, ln2b, nullptr, xbf);

    // MLP1: N=3072, BN=128, grid 24x64, gelu
    k_gemm<128><<<dim3(24, 64), 256, 0, stream>>>(
        xbf, mW1T, mb1, nullptr, nullptr, nullptr, nullptr, midbf, nullptr, nullptr, M, F, C, 1, 0, 0);

    // MLP2: N=768, K=3072, BN=64, resid=x2 -> out (f32)
    k_gemm<64><<<dim3(12, 64), 256, 0, stream>>>(
        midbf, mW2T, mb2, nullptr, nullptr, x2, out, nullptr, nullptr, nullptr, M, C, F, 0, 0, 0);
}